// Round 12
// baseline (877.085 us; speedup 1.0000x reference)
//
#include <hip/hip_runtime.h>
#include <stdint.h>

// ---------------- problem constants ----------------
#define HW    576
#define CIN   48
#define NB    1024

// output element offsets (flat fp32: center,kp,reg,off,norm,pix)
#define O_CENTER 0L
#define O_KP     589824L
#define O_REG    2949120L
#define O_OFF    7667712L
#define O_NORM   12386304L
#define O_PIX    12394496L

// workspace byte offsets (total 174,752 B)
#define WS_A1    0        // bf16 conv1 A-table [9sh][3k16][2g][96row][8ci] = 82944 B
#define WS_W2A   82944    // bf16 conv2 A-table [6k16][2g][32oc][8k]       = 6144 B
#define WS_B1A   89088    // fp32 folded bias1 [96]
#define WS_B2A   89472    // fp32 bias2 [32]
#define WS_WKPT  89600    // fp32 kp conv1 weights [ci48][k9][mid24] = 41472 B
#define WS_B1KP  131072   // fp32 [24]
#define WS_W2KP  131168   // fp32 [4][24]
#define WS_B2KP  131552   // fp32 [4]
#define WS_WOFFT 131584   // fp32 off conv1 weights TRANSPOSED [mid24][ci48][k9] = 41472 B
#define WS_B1OFF 173056   // fp32 [24]
#define WS_W2OFF 173152   // fp32 [16][24]
#define WS_B2OFF 174688   // fp32 [16]

typedef short bf16x8 __attribute__((ext_vector_type(8)));
typedef float f32x16 __attribute__((ext_vector_type(16)));

union U4B  { uint4 q; bf16x8 v; };
union U16Q { uint16_t u[8]; uint4 q; };
union U4Q  { uint16_t u[4]; uint2 q; };

__device__ __forceinline__ bf16x8 as_bf(uint4 q){ U4B u; u.q = q; return u.v; }
__device__ __forceinline__ uint16_t f2b(float f){
  union { float f; uint32_t i; } x; x.f = f;
  uint32_t r = x.i + 0x7FFFu + ((x.i >> 16) & 1u);   // RNE
  return (uint16_t)(r >> 16);
}

struct P32 {
  const float* w1[4]; const float* b1[4]; const float* g[4]; const float* be[4];
  const float* m[4];  const float* v[4];  const float* w2[4]; const float* b2[4];
};

// oc (0..20) -> head, local channel. order: center(1), kp(4), reg(8), off(8)
__device__ __forceinline__ void oc_decode(int oc, int& h, int& ch){
  if (oc == 0){ h = 0; ch = 0; }
  else if (oc < 5){ h = 1; ch = oc - 1; }
  else if (oc < 13){ h = 2; ch = oc - 5; }
  else { h = 3; ch = oc - 13; }
}

// ---------------- K0: build all tables in ws, PARALLELIZED 48 blocks ----------------
// (R10-proven: grid-strided over 48 blocks, bit-identical workspace bytes.)
#define PREP_BLOCKS 48
__global__ void prep_kernel(P32 P, char* __restrict__ wsb){
  const int tid = threadIdx.x, bid = blockIdx.x;
  const int g0 = bid*256 + tid;
  const int STR = PREP_BLOCKS*256;
  __shared__ float sc[96], bfold[96];
  if (tid < 96){
    int h = tid / 24, o = tid % 24;
    float s = P.g[h][o] / sqrtf(P.v[h][o] + 1e-5f);   // known-good fold
    sc[tid] = s;
    bfold[tid] = (P.b1[h][o] - P.m[h][o]) * s + P.be[h][o];
  }
  __syncthreads();
  uint16_t* A1 = (uint16_t*)(wsb + WS_A1);
  for (int t = g0; t < 41472; t += STR){
    int j = t & 7, slot = t >> 3;
    int row = slot % 96, sk = slot / 96;
    int g = sk & 1, k3 = (sk >> 1) % 3, sh = (sk >> 1) / 3;
    int ci = k3*16 + g*8 + j;
    int h = row / 24, o = row % 24;
    A1[t] = f2b(P.w1[h][(o*CIN + ci)*9 + sh] * sc[row]);
  }
  uint16_t* W2A = (uint16_t*)(wsb + WS_W2A);
  for (int t = g0; t < 3072; t += STR){
    int j = t & 7, slot = t >> 3;
    int oc = slot & 31, kg = slot >> 5;
    int k = kg*8 + j;
    float val = 0.f;
    if (oc < 21){
      int h, ch; oc_decode(oc, h, ch);
      int hk = k / 24, o = k % 24;
      if (hk == h) val = P.w2[h][ch*24 + o];
    }
    W2A[t] = f2b(val);
  }
  // kp exact tables (fp32), [ci][k][mid]
  float* WKPT = (float*)(wsb + WS_WKPT);
  for (int t = g0; t < 10368; t += STR){
    int o = t % 24, k = (t/24) % 9, ci = t / 216;
    WKPT[t] = P.w1[1][(o*CIN + ci)*9 + k] * sc[24 + o];
  }
  // off exact table, TRANSPOSED [mid][ci][k] == w1's natural layout
  float* WOFFT = (float*)(wsb + WS_WOFFT);
  for (int t = g0; t < 10368; t += STR){
    int o = t / 432;
    WOFFT[t] = P.w1[3][t] * sc[72 + o];
  }
  if (bid == 0){
    float* B1A = (float*)(wsb + WS_B1A);
    if (tid < 96) B1A[tid] = bfold[tid];
    float* B2A = (float*)(wsb + WS_B2A);
    if (tid < 32){
      float v = 0.f;
      if (tid < 21){ int h, ch; oc_decode(tid, h, ch); v = P.b2[h][ch]; }
      B2A[tid] = v;
    }
    if (tid < 24) ((float*)(wsb + WS_B1KP))[tid] = bfold[24 + tid];
    if (tid < 96) ((float*)(wsb + WS_W2KP))[tid] = P.w2[1][tid];
    if (tid < 4)  ((float*)(wsb + WS_B2KP))[tid] = P.b2[1][tid];
    if (tid < 24) ((float*)(wsb + WS_B1OFF))[tid] = bfold[72 + tid];
    for (int t = tid; t < 384; t += 256) ((float*)(wsb + WS_W2OFF))[t] = P.w2[3][t];
    if (tid < 16) ((float*)(wsb + WS_B2OFF))[tid] = P.b2[3][tid];
  }
}

// ---------------- K1: MFMA conv per batch (dense outputs only) ----------------
// R11 post-mortem: A1-LDS staging was NEUTRAL -> L2 latency not critical. The
// occupancy cap is REGISTERS: VGPR 76 (reported, excl. acc) + 96 AGPR acc
// (acc[3][2] f32x16) = 172/thread -> 2 waves/SIMD = 8 waves/CU = the measured
// 25% occupancy, with LDS slack unused. Fix: split the pixel halves (st2) into
// two SEQUENTIAL passes (unroll-disabled), each with acc[3] (48 regs), and
// fuse conv2 per-mt (c2 += 2 k6-steps right after each mt's ybuf rows), so
// ybuf = 2KB/wave in a SEPARATE region (no aliasing -> mid-kernel barrier
// gone; image persists across passes). Peak regs ~48+16 AGPR + ~76 VGPR ->
// ~140 -> 3 waves/SIMD (+50%). Outputs BIT-IDENTICAL: per-acc[mt] chain keeps
// (sh,k3) order; c2 keeps k6 0..5 order; A1 L2 reads double (+81/wave, proven
// cheap by R11). LDS 78,432 B -> still 2 blocks by LDS.
__global__ __launch_bounds__(576) void conv_main(
    const float* __restrict__ feat, const char* __restrict__ wsb,
    float* __restrict__ out)
{
  __shared__ __align__(16) char smem[78432];      // [0,60000) image, [60000,78432) ybuf 9x2048
  const int b = blockIdx.x, tid = threadIdx.x;
  const int wave = tid >> 6, lane = tid & 63;
  const int q = lane >> 5, l31 = lane & 31;

  if (tid < 294){                                 // zero border row y'=0, col x'=0
    int cib = tid / 49, r = tid % 49;
    int slot = cib*625 + ((r < 25) ? r : (r - 24)*25);
    *(uint4*)(smem + slot*16) = make_uint4(0,0,0,0);
  }
  {
    const float* fb = feat + (size_t)b * (CIN*HW);
    int p = tid, py = p / 24, px = p % 24;
    int sbase = (py+1)*25 + (px+1);
    for (int cib = 0; cib < 6; ++cib){
      U16Q t8;
      #pragma unroll
      for (int j = 0; j < 8; ++j) t8.u[j] = f2b(fb[(cib*8 + j)*HW + p]);
      *(uint4*)(smem + (cib*625 + sbase)*16) = t8.q;
    }
  }
  __syncthreads();

  const int p0 = wave*64 + l31;
  const uint4* A1 = (const uint4*)(wsb + WS_A1);
  const float* B1A = (const float*)(wsb + WS_B1A);
  const float* B2A = (const float*)(wsb + WS_B2A);
  const uint4* W2A = (const uint4*)(wsb + WS_W2A);
  char* ybuf = smem + 60000 + wave*2048;
  const uint4 zz = make_uint4(0,0,0,0);

  #pragma clang loop unroll(disable)
  for (int st2 = 0; st2 < 2; ++st2){
    const int p = p0 + st2*32;
    const int py = p / 24, px = p % 24;
    f32x16 acc[3] = {};

    for (int sh = 0; sh < 9; ++sh){
      const int ky = sh / 3, kx = sh % 3;
      const int yb = py + ky, xb = px + kx;
      const bool v = (yb < 25) && (xb < 25);
      const int so = yb*25 + xb;
      #pragma unroll
      for (int k3 = 0; k3 < 3; ++k3){
        const int cib = k3*2 + q;
        uint4 r = *(const uint4*)(smem + (cib*625 + (v ? so : 0))*16);
        r = v ? r : zz;
        const bf16x8 bf = as_bf(r);
        const int abase = ((sh*3 + k3)*2 + q)*96 + l31;
        #pragma unroll
        for (int mt = 0; mt < 3; ++mt){
          const bf16x8 af = as_bf(A1[abase + mt*32]);
          acc[mt] = __builtin_amdgcn_mfma_f32_32x32x16_bf16(af, bf, acc[mt], 0, 0, 0);
        }
      }
    }

    // fused conv2: per mt, write this mt's 4 ybuf rows, then 2 k6 MFMA steps.
    // c2 accumulates k6 = 0..5 in order (bit-identical to the staged version).
    f32x16 c2 = {};
    #pragma unroll
    for (int mt = 0; mt < 3; ++mt){
      #pragma unroll
      for (int rg = 0; rg < 4; ++rg){
        const int chanbase = mt*32 + rg*8 + q*4;
        const float* bp = B1A + chanbase;
        U4Q t4;
        #pragma unroll
        for (int r0 = 0; r0 < 4; ++r0){
          float y = acc[mt][rg*4 + r0] + bp[r0];
          t4.u[r0] = f2b(fmaxf(y, 0.f));
        }
        *(uint2*)(ybuf + (rg*32 + l31)*16 + q*8) = t4.q;
      }
      #pragma unroll
      for (int s = 0; s < 2; ++s){
        const int k6 = mt*2 + s;
        const bf16x8 yf = as_bf(*(const uint4*)(ybuf + ((s*2 + q)*32 + l31)*16));
        const bf16x8 wf = as_bf(W2A[(k6*2 + q)*32 + l31]);
        c2 = __builtin_amdgcn_mfma_f32_32x32x16_bf16(wf, yf, c2, 0, 0, 0);
      }
    }

    #pragma unroll
    for (int r = 0; r < 16; ++r){
      const int oc = (r & 3) + 8*(r >> 2) + 4*q;
      if (oc < 21){
        float v = c2[r] + B2A[oc];
        long base; int sig;
        if (oc == 0){ base = O_CENTER + (long)b*HW; sig = 1; }
        else if (oc < 5){ base = O_KP + ((long)b*4 + (oc-1))*HW; sig = 1; }
        else if (oc < 13){ base = O_REG + ((long)b*8 + (oc-5))*HW; sig = 0; }
        else { base = O_OFF + ((long)b*8 + (oc-13))*HW; sig = 0; }
        out[base + p] = sig ? (1.f / (1.f + __expf(-v))) : v;
      }
    }
  }
}

// ---------------- K2: candidate-filtered exact kp argmax + offsets ----------------
// BYTE-IDENTICAL to the R8-proven version.
__global__ __launch_bounds__(576) void kp_select(
    const float* __restrict__ feat, const char* __restrict__ wsb,
    float* __restrict__ out)
{
  __shared__ __align__(16) float simg[8*26*24];   // 19,968 B
  __shared__ float wk_lds[8*9*24];                //  6,912 B  [c8][k][mid]
  __shared__ float ykp [96*24];                   //  9,216 B  [group-slot][mid]
  __shared__ __align__(16) float opatch[4][432];  //  6,912 B  winner patches
  __shared__ float ymidL[4*24];                   //    384 B  winner off-mids
  __shared__ int   jobL[4*HW];                    //  9,216 B  (n<<16)|p
  __shared__ int   KtotL;
  __shared__ unsigned long long bestL[4];

  const int b = blockIdx.x, tid = threadIdx.x;
  if (tid == 0) KtotL = 0;
  if (tid < 4) bestL[tid] = 0ULL;
  __syncthreads();

  // ---- Phase 1: per-head sigmoid max + candidate collection (proven) ----
  if (tid < 256){
    const int n = tid >> 6, ln = tid & 63;
    const float* sp = out + O_KP + ((long)b*4 + n)*HW;
    float s[9];
    #pragma unroll
    for (int j = 0; j < 9; ++j) s[j] = sp[j*64 + ln];
    float mx = s[0];
    #pragma unroll
    for (int j = 1; j < 9; ++j) mx = fmaxf(mx, s[j]);
    #pragma unroll
    for (int off = 32; off >= 1; off >>= 1)
      mx = fmaxf(mx, __shfl_xor(mx, off, 64));
    const float sm = fminf(mx, 0.999999f);        // clamp: thr only gets safer
    const float thr = sm / (sm + (1.f - sm) * 1.1331485f);  // e^0.125
    #pragma unroll
    for (int j = 0; j < 9; ++j){
      if (s[j] >= thr){
        const int slot = atomicAdd(&KtotL, 1);
        jobL[slot] = (n << 16) | (j*64 + ln);
      }
    }
  }
  __syncthreads();
  const int Ktot = KtotL;

  const int s24 = tid / 24, omid = tid - s24*24;  // cand slot 0..23, mid 0..23
  const int dst = (s24 + 1)*24 + omid;            // staging dest (old mapping)
  const float* fb = feat + (size_t)b * (CIN*HW);
  const float* WKPT = (const float*)(wsb + WS_WKPT);
  const float b1k = ((const float*)(wsb + WS_B1KP))[omid];

  for (int g0 = 0; g0 < Ktot; g0 += 96){
    const int Kg = min(96, Ktot - g0);            // cands this group (uniform)

    int pyc[4], pxc[4];
    #pragma unroll
    for (int c = 0; c < 4; ++c){
      int p = 0;
      if (c*24 + s24 < Kg) p = jobL[g0 + c*24 + s24] & 0xFFFF;
      pyc[c] = p / 24; pxc[c] = p - (p/24)*24;
    }

    float acck[4] = {0.f,0.f,0.f,0.f};

    for (int pass = 0; pass < 6; ++pass){
      __syncthreads();                            // protect previous pass reads
      if (tid < 384){                             // zero pad rows 0 and 25
        int c = tid / 48, r = tid - c*48;
        int row = (r < 24) ? 0 : 25;
        int col = (r < 24) ? r : r - 24;
        simg[c*624 + row*24 + col] = 0.f;
      }
      #pragma unroll
      for (int c = 0; c < 8; ++c)
        simg[c*624 + dst] = fb[(pass*8 + c)*HW + tid];
      #pragma unroll
      for (int j = 0; j < 3; ++j)                 // 1728 = 3*576: weight slice
        wk_lds[tid + j*576] = WKPT[pass*1728 + tid + j*576];
      __syncthreads();

      for (int c8 = 0; c8 < 8; ++c8){
        float pch[4][9];
        #pragma unroll
        for (int c = 0; c < 4; ++c) if (c*24 < Kg){
          const int a = c8*624 + pyc[c]*24 + pxc[c];
          const bool wl = (pxc[c] > 0), wr = (pxc[c] < 23);
          #pragma unroll
          for (int dr = 0; dr < 3; ++dr){
            const int aa = a + dr*24;
            pch[c][dr*3+0] = wl ? simg[aa-1] : 0.f;
            pch[c][dr*3+1] = simg[aa];
            pch[c][dr*3+2] = wr ? simg[aa+1] : 0.f;
          }
        }
        const float* wkb = wk_lds + c8*216 + omid;
        #pragma unroll
        for (int k = 0; k < 9; ++k){
          const float wk = wkb[k*24];
          #pragma unroll
          for (int c = 0; c < 4; ++c) if (c*24 < Kg)
            acck[c] = fmaf(pch[c][k], wk, acck[c]);
        }
      }
    }

    // mids -> LDS
    #pragma unroll
    for (int c = 0; c < 4; ++c) if (c*24 < Kg){
      const int sl = c*24 + s24;
      ykp[sl*24 + omid] = fmaxf(acck[c] + b1k, 0.f);
    }
    __syncthreads();

    // kp layer-2 + winner update (one thread per candidate in group)
    if (tid < Kg){
      const int cand = g0 + tid;
      const int job = jobL[cand];
      const int n = job >> 16, p = job & 0xFFFF;
      const float* W2KP = (const float*)(wsb + WS_W2KP);
      float v = ((const float*)(wsb + WS_B2KP))[n];
      #pragma unroll
      for (int o = 0; o < 24; ++o)
        v = fmaf(ykp[tid*24 + o], W2KP[n*24 + o], v);
      union { float f; uint32_t u; } cv; cv.f = v;
      const uint32_t key = cv.u ^ (uint32_t)(((int32_t)cv.u >> 31) | (int32_t)0x80000000);
      const unsigned long long pk =
          ((unsigned long long)key << 32) | (unsigned)(1023 - p);
      atomicMax(&bestL[n], pk);
    }
    __syncthreads();
  }

  // ---- Phase 3: gather the 4 winners' patches global->LDS (parallel) ----
  #pragma unroll
  for (int j = 0; j < 3; ++j){
    const int e = tid*3 + j;
    const int w = e / 432, idx = e - w*432;
    const int ci = idx / 9, k = idx - ci*9;
    const int p = 1023 - (int)(bestL[w] & 0xFFFFFFFFu);
    const int py = p / 24, px = p % 24;
    const int yy = py + k/3 - 1, xx = px + (k - (k/3)*3) - 1;
    float v = 0.f;
    if (yy >= 0 && yy < 24 && xx >= 0 && xx < 24)
      v = fb[ci*HW + yy*24 + xx];
    opatch[w][idx] = v;
  }
  __syncthreads();

  // ---- Phase 4: exact off-head mids at winners (96 threads: n x mid) ----
  if (tid < 96){
    const int n = tid / 24, mid = tid - n*24;
    const float* wrow = (const float*)(wsb + WS_WOFFT) + mid*432;
    const float* prow = opatch[n];
    float s = 0.f;
    #pragma unroll 4
    for (int t = 0; t < 108; ++t){                // 108 float4 = 432 terms
      const float4 pv = *(const float4*)(prow + t*4);
      const float4 wv = *(const float4*)(wrow + t*4);
      s = fmaf(pv.x, wv.x, s);
      s = fmaf(pv.y, wv.y, s);
      s = fmaf(pv.z, wv.z, s);
      s = fmaf(pv.w, wv.w, s);
    }
    ymidL[n*24 + mid] = fmaxf(s + ((const float*)(wsb + WS_B1OFF))[mid], 0.f);
  }
  __syncthreads();

  // ---- Phase 5: off layer-2 at winners, norm/pix ----
  if (tid < 4){
    const int n = tid;
    const int p = 1023 - (int)(bestL[n] & 0xFFFFFFFFu);
    const int py = p / 24, px = p % 24;
    const float* W2OFF = (const float*)(wsb + WS_W2OFF);
    const float* B2OFF = (const float*)(wsb + WS_B2OFF);
    float ox = B2OFF[2*n], oy = B2OFF[2*n + 1];
    #pragma unroll
    for (int o = 0; o < 24; ++o){
      const float ym = ymidL[n*24 + o];
      ox = fmaf(ym, W2OFF[(2*n)*24 + o], ox);
      oy = fmaf(ym, W2OFF[(2*n + 1)*24 + o], oy);
    }
    const float fx = ((float)px + ox) * 4.f - 112.f;  // SCALE=4, X0=-112
    const float fy = ((float)py + oy) * 4.f;          // Y0=0
    out[O_NORM + b*8 + 2*n    ] = (fx + 112.f) * (1.f/336.f);
    out[O_NORM + b*8 + 2*n + 1] = fy * (1.f/224.f);
    out[O_PIX  + b*8 + 2*n    ] = fx;
    out[O_PIX  + b*8 + 2*n + 1] = fy;
  }
}

// ---------------- launch ----------------
extern "C" void kernel_launch(void* const* d_in, const int* in_sizes, int n_in,
                              void* d_out, int out_size, void* d_ws, size_t ws_size,
                              hipStream_t stream)
{
  const float* feat = (const float*)d_in[0];
  P32 P;
  for (int h = 0; h < 4; ++h){
    const int base = 1 + h*8;
    P.w1[h] = (const float*)d_in[base+0];
    P.b1[h] = (const float*)d_in[base+1];
    P.g[h]  = (const float*)d_in[base+2];
    P.be[h] = (const float*)d_in[base+3];
    P.m[h]  = (const float*)d_in[base+4];
    P.v[h]  = (const float*)d_in[base+5];
    P.w2[h] = (const float*)d_in[base+6];
    P.b2[h] = (const float*)d_in[base+7];
  }
  char* wsb = (char*)d_ws;
  float* out = (float*)d_out;

  prep_kernel<<<dim3(PREP_BLOCKS), 256, 0, stream>>>(P, wsb);
  conv_main  <<<dim3(NB),          576, 0, stream>>>(feat, wsb, out);
  kp_select  <<<dim3(NB),          576, 0, stream>>>(feat, wsb, out);
}

// Round 13
// 611.270 us; speedup vs baseline: 1.4349x; 1.4349x over previous
//
#include <hip/hip_runtime.h>
#include <stdint.h>

// ---------------- problem constants ----------------
#define HW    576
#define CIN   48
#define NB    1024

// output element offsets (flat fp32: center,kp,reg,off,norm,pix)
#define O_CENTER 0L
#define O_KP     589824L
#define O_REG    2949120L
#define O_OFF    7667712L
#define O_NORM   12386304L
#define O_PIX    12394496L

// workspace byte offsets (total 174,752 B)
#define WS_A1    0        // bf16 conv1 A-table [9sh][3k16][2g][96row][8ci] = 82944 B
#define WS_W2A   82944    // bf16 conv2 A-table [6k16][2g][32oc][8k]       = 6144 B
#define WS_B1A   89088    // fp32 folded bias1 [96]
#define WS_B2A   89472    // fp32 bias2 [32]
#define WS_WKPT  89600    // fp32 kp conv1 weights TRANSPOSED [mid24][ci48][k9] = 41472 B
#define WS_B1KP  131072   // fp32 [24]
#define WS_W2KP  131168   // fp32 [4][24]
#define WS_B2KP  131552   // fp32 [4]
#define WS_WOFFT 131584   // fp32 off conv1 weights TRANSPOSED [mid24][ci48][k9] = 41472 B
#define WS_B1OFF 173056   // fp32 [24]
#define WS_W2OFF 173152   // fp32 [16][24]
#define WS_B2OFF 174688   // fp32 [16]

typedef short bf16x8 __attribute__((ext_vector_type(8)));
typedef float f32x16 __attribute__((ext_vector_type(16)));

union U4B  { uint4 q; bf16x8 v; };
union U16Q { uint16_t u[8]; uint4 q; };
union U4Q  { uint16_t u[4]; uint2 q; };

__device__ __forceinline__ bf16x8 as_bf(uint4 q){ U4B u; u.q = q; return u.v; }
__device__ __forceinline__ uint16_t f2b(float f){
  union { float f; uint32_t i; } x; x.f = f;
  uint32_t r = x.i + 0x7FFFu + ((x.i >> 16) & 1u);   // RNE
  return (uint16_t)(r >> 16);
}

struct P32 {
  const float* w1[4]; const float* b1[4]; const float* g[4]; const float* be[4];
  const float* m[4];  const float* v[4];  const float* w2[4]; const float* b2[4];
};

// oc (0..20) -> head, local channel. order: center(1), kp(4), reg(8), off(8)
__device__ __forceinline__ void oc_decode(int oc, int& h, int& ch){
  if (oc == 0){ h = 0; ch = 0; }
  else if (oc < 5){ h = 1; ch = oc - 1; }
  else if (oc < 13){ h = 2; ch = oc - 5; }
  else { h = 3; ch = oc - 13; }
}

// ---------------- K0: build all tables in ws, PARALLELIZED 48 blocks ----------------
// (R10-proven structure; WKPT now TRANSPOSED [mid][ci][k] like WOFFT — this is
// w1's natural layout, so the fill is a straight scale.)
#define PREP_BLOCKS 48
__global__ void prep_kernel(P32 P, char* __restrict__ wsb){
  const int tid = threadIdx.x, bid = blockIdx.x;
  const int g0 = bid*256 + tid;
  const int STR = PREP_BLOCKS*256;
  __shared__ float sc[96], bfold[96];
  if (tid < 96){
    int h = tid / 24, o = tid % 24;
    float s = P.g[h][o] / sqrtf(P.v[h][o] + 1e-5f);   // known-good fold
    sc[tid] = s;
    bfold[tid] = (P.b1[h][o] - P.m[h][o]) * s + P.be[h][o];
  }
  __syncthreads();
  uint16_t* A1 = (uint16_t*)(wsb + WS_A1);
  for (int t = g0; t < 41472; t += STR){
    int j = t & 7, slot = t >> 3;
    int row = slot % 96, sk = slot / 96;
    int g = sk & 1, k3 = (sk >> 1) % 3, sh = (sk >> 1) / 3;
    int ci = k3*16 + g*8 + j;
    int h = row / 24, o = row % 24;
    A1[t] = f2b(P.w1[h][(o*CIN + ci)*9 + sh] * sc[row]);
  }
  uint16_t* W2A = (uint16_t*)(wsb + WS_W2A);
  for (int t = g0; t < 3072; t += STR){
    int j = t & 7, slot = t >> 3;
    int oc = slot & 31, kg = slot >> 5;
    int k = kg*8 + j;
    float val = 0.f;
    if (oc < 21){
      int h, ch; oc_decode(oc, h, ch);
      int hk = k / 24, o = k % 24;
      if (hk == h) val = P.w2[h][ch*24 + o];
    }
    W2A[t] = f2b(val);
  }
  // kp exact table, TRANSPOSED [mid][ci][k]: t = o*432 + ci*9 + k
  float* WKPT = (float*)(wsb + WS_WKPT);
  for (int t = g0; t < 10368; t += STR){
    int o = t / 432;
    WKPT[t] = P.w1[1][t] * sc[24 + o];
  }
  // off exact table, TRANSPOSED [mid][ci][k]
  float* WOFFT = (float*)(wsb + WS_WOFFT);
  for (int t = g0; t < 10368; t += STR){
    int o = t / 432;
    WOFFT[t] = P.w1[3][t] * sc[72 + o];
  }
  if (bid == 0){
    float* B1A = (float*)(wsb + WS_B1A);
    if (tid < 96) B1A[tid] = bfold[tid];
    float* B2A = (float*)(wsb + WS_B2A);
    if (tid < 32){
      float v = 0.f;
      if (tid < 21){ int h, ch; oc_decode(tid, h, ch); v = P.b2[h][ch]; }
      B2A[tid] = v;
    }
    if (tid < 24) ((float*)(wsb + WS_B1KP))[tid] = bfold[24 + tid];
    if (tid < 96) ((float*)(wsb + WS_W2KP))[tid] = P.w2[1][tid];
    if (tid < 4)  ((float*)(wsb + WS_B2KP))[tid] = P.b2[1][tid];
    if (tid < 24) ((float*)(wsb + WS_B1OFF))[tid] = bfold[72 + tid];
    for (int t = tid; t < 384; t += 256) ((float*)(wsb + WS_W2OFF))[t] = P.w2[3][t];
    if (tid < 16) ((float*)(wsb + WS_B2OFF))[tid] = P.b2[3][tid];
  }
}

// ---------------- K1: MFMA conv per batch (dense outputs only) ----------------
// BYTE-IDENTICAL to the R8/R10-proven kernel (216us). Three restructure
// attempts all failed: R9 spatial split (VGPR 128, regression), R11 A1-LDS
// staging (neutral), R12 acc-split (scratch spill, 870MB writes). This
// codegen is a verified local optimum — do not perturb.
__global__ __launch_bounds__(576) void conv_main(
    const float* __restrict__ feat, const char* __restrict__ wsb,
    float* __restrict__ out)
{
  __shared__ __align__(16) char smem[60000];
  const int b = blockIdx.x, tid = threadIdx.x;
  const int wave = tid >> 6, lane = tid & 63;
  const int q = lane >> 5, l31 = lane & 31;

  if (tid < 294){                                 // zero border row y'=0, col x'=0
    int cib = tid / 49, r = tid % 49;
    int slot = cib*625 + ((r < 25) ? r : (r - 24)*25);
    *(uint4*)(smem + slot*16) = make_uint4(0,0,0,0);
  }
  {
    const float* fb = feat + (size_t)b * (CIN*HW);
    int p = tid, py = p / 24, px = p % 24;
    int sbase = (py+1)*25 + (px+1);
    for (int cib = 0; cib < 6; ++cib){
      U16Q t8;
      #pragma unroll
      for (int j = 0; j < 8; ++j) t8.u[j] = f2b(fb[(cib*8 + j)*HW + p]);
      *(uint4*)(smem + (cib*625 + sbase)*16) = t8.q;
    }
  }
  __syncthreads();

  f32x16 acc[3][2] = {};
  const int p0 = wave*64 + l31, p1 = p0 + 32;
  const int py0 = p0/24, px0 = p0%24, py1 = p1/24, px1 = p1%24;
  const uint4* A1 = (const uint4*)(wsb + WS_A1);
  const uint4 zz = make_uint4(0,0,0,0);

  for (int sh = 0; sh < 9; ++sh){
    const int ky = sh / 3, kx = sh % 3;
    const int yb0 = py0 + ky, xb0 = px0 + kx;
    const int yb1 = py1 + ky, xb1 = px1 + kx;
    const bool v0 = (yb0 < 25) && (xb0 < 25);
    const bool v1 = (yb1 < 25) && (xb1 < 25);
    const int so0 = yb0*25 + xb0, so1 = yb1*25 + xb1;
    #pragma unroll
    for (int k3 = 0; k3 < 3; ++k3){
      const int cib = k3*2 + q;
      uint4 r0 = *(const uint4*)(smem + (cib*625 + (v0 ? so0 : 0))*16);
      uint4 r1 = *(const uint4*)(smem + (cib*625 + (v1 ? so1 : 0))*16);
      r0 = v0 ? r0 : zz;
      r1 = v1 ? r1 : zz;
      const bf16x8 bf0 = as_bf(r0), bf1 = as_bf(r1);
      const int abase = ((sh*3 + k3)*2 + q)*96 + l31;
      #pragma unroll
      for (int mt = 0; mt < 3; ++mt){
        const bf16x8 af = as_bf(A1[abase + mt*32]);
        acc[mt][0] = __builtin_amdgcn_mfma_f32_32x32x16_bf16(af, bf0, acc[mt][0], 0, 0, 0);
        acc[mt][1] = __builtin_amdgcn_mfma_f32_32x32x16_bf16(af, bf1, acc[mt][1], 0, 0, 0);
      }
    }
  }
  __syncthreads();                                // image dead; reuse LDS

  const float* B1A = (const float*)(wsb + WS_B1A);
  const float* B2A = (const float*)(wsb + WS_B2A);
  const uint4* W2A = (const uint4*)(wsb + WS_W2A);
  char* ybuf = smem + wave*6144;

  #pragma unroll
  for (int st2 = 0; st2 < 2; ++st2){
    const int p = st2 ? p1 : p0;
    #pragma unroll
    for (int mt = 0; mt < 3; ++mt){
      #pragma unroll
      for (int rg = 0; rg < 4; ++rg){
        const int chanbase = mt*32 + rg*8 + q*4;
        const float* bp = B1A + chanbase;
        U4Q t4;
        #pragma unroll
        for (int r0 = 0; r0 < 4; ++r0){
          float y = acc[mt][st2][rg*4 + r0] + bp[r0];
          t4.u[r0] = f2b(fmaxf(y, 0.f));
        }
        *(uint2*)(ybuf + ((mt*4 + rg)*32 + l31)*16 + q*8) = t4.q;
      }
    }
    f32x16 c2 = {};
    #pragma unroll
    for (int k6 = 0; k6 < 6; ++k6){
      const bf16x8 yf = as_bf(*(const uint4*)(ybuf + ((k6*2 + q)*32 + l31)*16));
      const bf16x8 wf = as_bf(W2A[(k6*2 + q)*32 + l31]);
      c2 = __builtin_amdgcn_mfma_f32_32x32x16_bf16(wf, yf, c2, 0, 0, 0);
    }
    #pragma unroll
    for (int r = 0; r < 16; ++r){
      const int oc = (r & 3) + 8*(r >> 2) + 4*q;
      if (oc < 21){
        float v = c2[r] + B2A[oc];
        long base; int sig;
        if (oc == 0){ base = O_CENTER + (long)b*HW; sig = 1; }
        else if (oc < 5){ base = O_KP + ((long)b*4 + (oc-1))*HW; sig = 1; }
        else if (oc < 13){ base = O_REG + ((long)b*8 + (oc-5))*HW; sig = 0; }
        else { base = O_OFF + ((long)b*8 + (oc-13))*HW; sig = 0; }
        out[base + p] = sig ? (1.f / (1.f + __expf(-v))) : v;
      }
    }
  }
}

// ---------------- K2: candidate-filtered exact kp argmax + offsets (v2) ----------------
// R8's version staged the full 48-ch image 6x per block (288 loads/thread +
// 12 barriers) to evaluate ~30-60 candidates. v2 gathers ONLY the candidate
// patches: per chunk of 24 cands, 24x432 elements -> LDS via 18 predicated
// parallel scattered loads/thread (Phase-3's proven pattern), then thread =
// (cand,mid) streams the TRANSPOSED weight row as float4 vs the LDS patch row
// (Phase-4's proven no-spill pattern, unroll 4). Chain order t=ci*9+k asc ==
// proven ci-major,k-inner; OOB stored 0 => fmaf(0,w,s)=s; layer-2 asc-o;
// winner pack identical -> all outputs bit-identical to R8. M=0.125 proven.
// opatch aliases patch[], ymidL aliases ykp[] (dead after selection):
// LDS ~53.3KB -> 3 blocks/CU. jobL capacity 2304 = max: no overflow path.
__global__ __launch_bounds__(576) void kp_select(
    const float* __restrict__ feat, const char* __restrict__ wsb,
    float* __restrict__ out)
{
  __shared__ __align__(16) float patch[24*432];   // 41,472 B (alias: opatch)
  __shared__ float ykp[24*24];                    //  2,304 B (alias: ymidL)
  __shared__ int   jobL[4*HW];                    //  9,216 B  (n<<16)|p
  __shared__ int   KtotL;
  __shared__ unsigned long long bestL[4];

  const int b = blockIdx.x, tid = threadIdx.x;
  if (tid == 0) KtotL = 0;
  if (tid < 4) bestL[tid] = 0ULL;
  __syncthreads();

  // ---- Phase 1: per-head sigmoid max + candidate collection (proven) ----
  if (tid < 256){
    const int n = tid >> 6, ln = tid & 63;
    const float* sp = out + O_KP + ((long)b*4 + n)*HW;
    float s[9];
    #pragma unroll
    for (int j = 0; j < 9; ++j) s[j] = sp[j*64 + ln];
    float mx = s[0];
    #pragma unroll
    for (int j = 1; j < 9; ++j) mx = fmaxf(mx, s[j]);
    #pragma unroll
    for (int off = 32; off >= 1; off >>= 1)
      mx = fmaxf(mx, __shfl_xor(mx, off, 64));
    const float sm = fminf(mx, 0.999999f);        // clamp: thr only gets safer
    const float thr = sm / (sm + (1.f - sm) * 1.1331485f);  // e^0.125
    #pragma unroll
    for (int j = 0; j < 9; ++j){
      if (s[j] >= thr){
        const int slot = atomicAdd(&KtotL, 1);
        jobL[slot] = (n << 16) | (j*64 + ln);
      }
    }
  }
  __syncthreads();
  const int Ktot = KtotL;

  const float* fb = feat + (size_t)b * (CIN*HW);
  const float* WKPT = (const float*)(wsb + WS_WKPT);
  const float* B1KP = (const float*)(wsb + WS_B1KP);
  const float* W2KP = (const float*)(wsb + WS_W2KP);
  const float* B2KP = (const float*)(wsb + WS_B2KP);
  const int ecand = tid / 24, emid = tid - ecand*24;  // eval mapping

  // ---- Phase 2: chunks of 24 candidates ----
  for (int g0 = 0; g0 < Ktot; g0 += 24){
    const int Kg = min(24, Ktot - g0);

    // gather 24x432 patch elements (18 predicated parallel loads/thread)
    #pragma unroll
    for (int j = 0; j < 18; ++j){
      const int e = j*576 + tid;
      const int cand = e / 432, idx = e - cand*432;
      if (cand < Kg){
        const int p = jobL[g0 + cand] & 0xFFFF;
        const int py = p / 24, px = p % 24;
        const int ci = idx / 9, k = idx - ci*9;
        const int yy = py + k/3 - 1, xx = px + (k - (k/3)*3) - 1;
        float v = 0.f;
        if (yy >= 0 && yy < 24 && xx >= 0 && xx < 24)
          v = fb[ci*HW + yy*24 + xx];
        patch[cand*432 + idx] = v;
      }
    }
    __syncthreads();

    // evaluate: thread = (cand, mid); float4 stream, proven no-spill pattern
    if (ecand < Kg){
      const float* wrow = WKPT + emid*432;
      const float* prow = patch + ecand*432;
      float s = 0.f;
      #pragma unroll 4
      for (int t = 0; t < 108; ++t){
        const float4 pv = *(const float4*)(prow + t*4);
        const float4 wv = *(const float4*)(wrow + t*4);
        s = fmaf(pv.x, wv.x, s);
        s = fmaf(pv.y, wv.y, s);
        s = fmaf(pv.z, wv.z, s);
        s = fmaf(pv.w, wv.w, s);
      }
      ykp[ecand*24 + emid] = fmaxf(s + B1KP[emid], 0.f);
    }
    __syncthreads();

    // layer-2 + winner update (one thread per candidate in chunk)
    if (tid < Kg){
      const int job = jobL[g0 + tid];
      const int n = job >> 16, p = job & 0xFFFF;
      float v = B2KP[n];
      #pragma unroll
      for (int o = 0; o < 24; ++o)
        v = fmaf(ykp[tid*24 + o], W2KP[n*24 + o], v);
      union { float f; uint32_t u; } cv; cv.f = v;
      const uint32_t key = cv.u ^ (uint32_t)(((int32_t)cv.u >> 31) | (int32_t)0x80000000);
      const unsigned long long pk =
          ((unsigned long long)key << 32) | (unsigned)(1023 - p);
      atomicMax(&bestL[n], pk);
    }
    __syncthreads();
  }

  // ---- Phase 3: gather the 4 winners' patches (opatch aliases patch) ----
  float* opatch = patch;
  #pragma unroll
  for (int j = 0; j < 3; ++j){
    const int e = tid*3 + j;
    const int w = e / 432, idx = e - w*432;
    const int ci = idx / 9, k = idx - ci*9;
    const int p = 1023 - (int)(bestL[w] & 0xFFFFFFFFu);
    const int py = p / 24, px = p % 24;
    const int yy = py + k/3 - 1, xx = px + (k - (k/3)*3) - 1;
    float v = 0.f;
    if (yy >= 0 && yy < 24 && xx >= 0 && xx < 24)
      v = fb[ci*HW + yy*24 + xx];
    opatch[w*432 + idx] = v;
  }
  __syncthreads();

  // ---- Phase 4: exact off-head mids at winners (96 threads: n x mid) ----
  float* ymidL = ykp;
  if (tid < 96){
    const int n = tid / 24, mid = tid - n*24;
    const float* wrow = (const float*)(wsb + WS_WOFFT) + mid*432;
    const float* prow = opatch + n*432;
    float s = 0.f;
    #pragma unroll 4
    for (int t = 0; t < 108; ++t){                // 108 float4 = 432 terms
      const float4 pv = *(const float4*)(prow + t*4);
      const float4 wv = *(const float4*)(wrow + t*4);
      s = fmaf(pv.x, wv.x, s);
      s = fmaf(pv.y, wv.y, s);
      s = fmaf(pv.z, wv.z, s);
      s = fmaf(pv.w, wv.w, s);
    }
    ymidL[n*24 + mid] = fmaxf(s + ((const float*)(wsb + WS_B1OFF))[mid], 0.f);
  }
  __syncthreads();

  // ---- Phase 5: off layer-2 at winners, norm/pix ----
  if (tid < 4){
    const int n = tid;
    const int p = 1023 - (int)(bestL[n] & 0xFFFFFFFFu);
    const int py = p / 24, px = p % 24;
    const float* W2OFF = (const float*)(wsb + WS_W2OFF);
    const float* B2OFF = (const float*)(wsb + WS_B2OFF);
    float ox = B2OFF[2*n], oy = B2OFF[2*n + 1];
    #pragma unroll
    for (int o = 0; o < 24; ++o){
      const float ym = ymidL[n*24 + o];
      ox = fmaf(ym, W2OFF[(2*n)*24 + o], ox);
      oy = fmaf(ym, W2OFF[(2*n + 1)*24 + o], oy);
    }
    const float fx = ((float)px + ox) * 4.f - 112.f;  // SCALE=4, X0=-112
    const float fy = ((float)py + oy) * 4.f;          // Y0=0
    out[O_NORM + b*8 + 2*n    ] = (fx + 112.f) * (1.f/336.f);
    out[O_NORM + b*8 + 2*n + 1] = fy * (1.f/224.f);
    out[O_PIX  + b*8 + 2*n    ] = fx;
    out[O_PIX  + b*8 + 2*n + 1] = fy;
  }
}

// ---------------- launch ----------------
extern "C" void kernel_launch(void* const* d_in, const int* in_sizes, int n_in,
                              void* d_out, int out_size, void* d_ws, size_t ws_size,
                              hipStream_t stream)
{
  const float* feat = (const float*)d_in[0];
  P32 P;
  for (int h = 0; h < 4; ++h){
    const int base = 1 + h*8;
    P.w1[h] = (const float*)d_in[base+0];
    P.b1[h] = (const float*)d_in[base+1];
    P.g[h]  = (const float*)d_in[base+2];
    P.be[h] = (const float*)d_in[base+3];
    P.m[h]  = (const float*)d_in[base+4];
    P.v[h]  = (const float*)d_in[base+5];
    P.w2[h] = (const float*)d_in[base+6];
    P.b2[h] = (const float*)d_in[base+7];
  }
  char* wsb = (char*)d_ws;
  float* out = (float*)d_out;

  prep_kernel<<<dim3(PREP_BLOCKS), 256, 0, stream>>>(P, wsb);
  conv_main  <<<dim3(NB),          576, 0, stream>>>(feat, wsb, out);
  kp_select  <<<dim3(NB),          576, 0, stream>>>(feat, wsb, out);
}

// Round 14
// 567.719 us; speedup vs baseline: 1.5449x; 1.0767x over previous
//
#include <hip/hip_runtime.h>
#include <stdint.h>

// ---------------- problem constants ----------------
#define HW    576
#define CIN   48
#define NB    1024

// output element offsets (flat fp32: center,kp,reg,off,norm,pix)
#define O_CENTER 0L
#define O_KP     589824L
#define O_REG    2949120L
#define O_OFF    7667712L
#define O_NORM   12386304L
#define O_PIX    12394496L

// workspace byte offsets (total 174,752 B)
#define WS_A1    0        // bf16 conv1 A-table [9sh][3k16][2g][96row][8ci] = 82944 B
#define WS_W2A   82944    // bf16 conv2 A-table [6k16][2g][32oc][8k]       = 6144 B
#define WS_B1A   89088    // fp32 folded bias1 [96]
#define WS_B2A   89472    // fp32 bias2 [32]
#define WS_WKPT  89600    // fp32 kp conv1 weights [ci48][k9][mid24] = 41472 B
#define WS_B1KP  131072   // fp32 [24]
#define WS_W2KP  131168   // fp32 [4][24]
#define WS_B2KP  131552   // fp32 [4]
#define WS_WOFFT 131584   // fp32 off conv1 weights TRANSPOSED [mid24][ci48][k9] = 41472 B
#define WS_B1OFF 173056   // fp32 [24]
#define WS_W2OFF 173152   // fp32 [16][24]
#define WS_B2OFF 174688   // fp32 [16]

typedef short bf16x8 __attribute__((ext_vector_type(8)));
typedef float f32x16 __attribute__((ext_vector_type(16)));

union U4B  { uint4 q; bf16x8 v; };
union U16Q { uint16_t u[8]; uint4 q; };
union U4Q  { uint16_t u[4]; uint2 q; };

__device__ __forceinline__ bf16x8 as_bf(uint4 q){ U4B u; u.q = q; return u.v; }
__device__ __forceinline__ uint16_t f2b(float f){
  union { float f; uint32_t i; } x; x.f = f;
  uint32_t r = x.i + 0x7FFFu + ((x.i >> 16) & 1u);   // RNE
  return (uint16_t)(r >> 16);
}

struct P32 {
  const float* w1[4]; const float* b1[4]; const float* g[4]; const float* be[4];
  const float* m[4];  const float* v[4];  const float* w2[4]; const float* b2[4];
};

// oc (0..20) -> head, local channel. order: center(1), kp(4), reg(8), off(8)
__device__ __forceinline__ void oc_decode(int oc, int& h, int& ch){
  if (oc == 0){ h = 0; ch = 0; }
  else if (oc < 5){ h = 1; ch = oc - 1; }
  else if (oc < 13){ h = 2; ch = oc - 5; }
  else { h = 3; ch = oc - 13; }
}

// ---------------- K0: build all tables in ws, PARALLELIZED 48 blocks ----------------
// (R10-proven: grid-strided over 48 blocks, bit-identical workspace bytes.)
#define PREP_BLOCKS 48
__global__ void prep_kernel(P32 P, char* __restrict__ wsb){
  const int tid = threadIdx.x, bid = blockIdx.x;
  const int g0 = bid*256 + tid;
  const int STR = PREP_BLOCKS*256;
  __shared__ float sc[96], bfold[96];
  if (tid < 96){
    int h = tid / 24, o = tid % 24;
    float s = P.g[h][o] / sqrtf(P.v[h][o] + 1e-5f);   // known-good fold
    sc[tid] = s;
    bfold[tid] = (P.b1[h][o] - P.m[h][o]) * s + P.be[h][o];
  }
  __syncthreads();
  uint16_t* A1 = (uint16_t*)(wsb + WS_A1);
  for (int t = g0; t < 41472; t += STR){
    int j = t & 7, slot = t >> 3;
    int row = slot % 96, sk = slot / 96;
    int g = sk & 1, k3 = (sk >> 1) % 3, sh = (sk >> 1) / 3;
    int ci = k3*16 + g*8 + j;
    int h = row / 24, o = row % 24;
    A1[t] = f2b(P.w1[h][(o*CIN + ci)*9 + sh] * sc[row]);
  }
  uint16_t* W2A = (uint16_t*)(wsb + WS_W2A);
  for (int t = g0; t < 3072; t += STR){
    int j = t & 7, slot = t >> 3;
    int oc = slot & 31, kg = slot >> 5;
    int k = kg*8 + j;
    float val = 0.f;
    if (oc < 21){
      int h, ch; oc_decode(oc, h, ch);
      int hk = k / 24, o = k % 24;
      if (hk == h) val = P.w2[h][ch*24 + o];
    }
    W2A[t] = f2b(val);
  }
  // kp exact tables (fp32), [ci][k][mid]
  float* WKPT = (float*)(wsb + WS_WKPT);
  for (int t = g0; t < 10368; t += STR){
    int o = t % 24, k = (t/24) % 9, ci = t / 216;
    WKPT[t] = P.w1[1][(o*CIN + ci)*9 + k] * sc[24 + o];
  }
  // off exact table, TRANSPOSED [mid][ci][k] == w1's natural layout
  float* WOFFT = (float*)(wsb + WS_WOFFT);
  for (int t = g0; t < 10368; t += STR){
    int o = t / 432;
    WOFFT[t] = P.w1[3][t] * sc[72 + o];
  }
  if (bid == 0){
    float* B1A = (float*)(wsb + WS_B1A);
    if (tid < 96) B1A[tid] = bfold[tid];
    float* B2A = (float*)(wsb + WS_B2A);
    if (tid < 32){
      float v = 0.f;
      if (tid < 21){ int h, ch; oc_decode(tid, h, ch); v = P.b2[h][ch]; }
      B2A[tid] = v;
    }
    if (tid < 24) ((float*)(wsb + WS_B1KP))[tid] = bfold[24 + tid];
    if (tid < 96) ((float*)(wsb + WS_W2KP))[tid] = P.w2[1][tid];
    if (tid < 4)  ((float*)(wsb + WS_B2KP))[tid] = P.b2[1][tid];
    if (tid < 24) ((float*)(wsb + WS_B1OFF))[tid] = bfold[72 + tid];
    for (int t = tid; t < 384; t += 256) ((float*)(wsb + WS_W2OFF))[t] = P.w2[3][t];
    if (tid < 16) ((float*)(wsb + WS_B2OFF))[tid] = P.b2[3][tid];
  }
}

// ---------------- K1: MFMA conv per batch (dense outputs only) ----------------
// R13 analysis: per-block wall = ~54us vs ~5us instruction model; MfmaUtil ==
// VALUBusy == 9%, HBM 8% -> memory-LATENCY-bound at ~9 waves/CU. The one
// serialized-memory phase is staging: interleaved load->f2b->ds_write caps
// outstanding loads at ~8/thread-group. Fix (THIS ROUND'S ONLY CHANGE): batch
// all 48 channel loads into registers first (48 independent global loads
// back-to-back, fully unrolled -> static indices, no scratch), then convert +
// write. Staged bytes and order identical; live range ends before acc goes
// live. Everything after __syncthreads is BYTE-IDENTICAL to the proven R8
// kernel (R9/R11/R12 restructures all failed; do not perturb the main loop).
__global__ __launch_bounds__(576) void conv_main(
    const float* __restrict__ feat, const char* __restrict__ wsb,
    float* __restrict__ out)
{
  __shared__ __align__(16) char smem[60000];
  const int b = blockIdx.x, tid = threadIdx.x;
  const int wave = tid >> 6, lane = tid & 63;
  const int q = lane >> 5, l31 = lane & 31;

  if (tid < 294){                                 // zero border row y'=0, col x'=0
    int cib = tid / 49, r = tid % 49;
    int slot = cib*625 + ((r < 25) ? r : (r - 24)*25);
    *(uint4*)(smem + slot*16) = make_uint4(0,0,0,0);
  }
  {
    const float* fb = feat + (size_t)b * (CIN*HW);
    int p = tid, py = p / 24, px = p % 24;
    int sbase = (py+1)*25 + (px+1);
    float v[48];
    #pragma unroll
    for (int c = 0; c < 48; ++c) v[c] = fb[c*HW + p];   // max MLP: 48 in flight
    #pragma unroll
    for (int cib = 0; cib < 6; ++cib){
      U16Q t8;
      #pragma unroll
      for (int j = 0; j < 8; ++j) t8.u[j] = f2b(v[cib*8 + j]);
      *(uint4*)(smem + (cib*625 + sbase)*16) = t8.q;
    }
  }
  __syncthreads();

  f32x16 acc[3][2] = {};
  const int p0 = wave*64 + l31, p1 = p0 + 32;
  const int py0 = p0/24, px0 = p0%24, py1 = p1/24, px1 = p1%24;
  const uint4* A1 = (const uint4*)(wsb + WS_A1);
  const uint4 zz = make_uint4(0,0,0,0);

  for (int sh = 0; sh < 9; ++sh){
    const int ky = sh / 3, kx = sh % 3;
    const int yb0 = py0 + ky, xb0 = px0 + kx;
    const int yb1 = py1 + ky, xb1 = px1 + kx;
    const bool v0 = (yb0 < 25) && (xb0 < 25);
    const bool v1 = (yb1 < 25) && (xb1 < 25);
    const int so0 = yb0*25 + xb0, so1 = yb1*25 + xb1;
    #pragma unroll
    for (int k3 = 0; k3 < 3; ++k3){
      const int cib = k3*2 + q;
      uint4 r0 = *(const uint4*)(smem + (cib*625 + (v0 ? so0 : 0))*16);
      uint4 r1 = *(const uint4*)(smem + (cib*625 + (v1 ? so1 : 0))*16);
      r0 = v0 ? r0 : zz;
      r1 = v1 ? r1 : zz;
      const bf16x8 bf0 = as_bf(r0), bf1 = as_bf(r1);
      const int abase = ((sh*3 + k3)*2 + q)*96 + l31;
      #pragma unroll
      for (int mt = 0; mt < 3; ++mt){
        const bf16x8 af = as_bf(A1[abase + mt*32]);
        acc[mt][0] = __builtin_amdgcn_mfma_f32_32x32x16_bf16(af, bf0, acc[mt][0], 0, 0, 0);
        acc[mt][1] = __builtin_amdgcn_mfma_f32_32x32x16_bf16(af, bf1, acc[mt][1], 0, 0, 0);
      }
    }
  }
  __syncthreads();                                // image dead; reuse LDS

  const float* B1A = (const float*)(wsb + WS_B1A);
  const float* B2A = (const float*)(wsb + WS_B2A);
  const uint4* W2A = (const uint4*)(wsb + WS_W2A);
  char* ybuf = smem + wave*6144;

  #pragma unroll
  for (int st2 = 0; st2 < 2; ++st2){
    const int p = st2 ? p1 : p0;
    #pragma unroll
    for (int mt = 0; mt < 3; ++mt){
      #pragma unroll
      for (int rg = 0; rg < 4; ++rg){
        const int chanbase = mt*32 + rg*8 + q*4;
        const float* bp = B1A + chanbase;
        U4Q t4;
        #pragma unroll
        for (int r0 = 0; r0 < 4; ++r0){
          float y = acc[mt][st2][rg*4 + r0] + bp[r0];
          t4.u[r0] = f2b(fmaxf(y, 0.f));
        }
        *(uint2*)(ybuf + ((mt*4 + rg)*32 + l31)*16 + q*8) = t4.q;
      }
    }
    f32x16 c2 = {};
    #pragma unroll
    for (int k6 = 0; k6 < 6; ++k6){
      const bf16x8 yf = as_bf(*(const uint4*)(ybuf + ((k6*2 + q)*32 + l31)*16));
      const bf16x8 wf = as_bf(W2A[(k6*2 + q)*32 + l31]);
      c2 = __builtin_amdgcn_mfma_f32_32x32x16_bf16(wf, yf, c2, 0, 0, 0);
    }
    #pragma unroll
    for (int r = 0; r < 16; ++r){
      const int oc = (r & 3) + 8*(r >> 2) + 4*q;
      if (oc < 21){
        float v = c2[r] + B2A[oc];
        long base; int sig;
        if (oc == 0){ base = O_CENTER + (long)b*HW; sig = 1; }
        else if (oc < 5){ base = O_KP + ((long)b*4 + (oc-1))*HW; sig = 1; }
        else if (oc < 13){ base = O_REG + ((long)b*8 + (oc-5))*HW; sig = 0; }
        else { base = O_OFF + ((long)b*8 + (oc-13))*HW; sig = 0; }
        out[base + p] = sig ? (1.f / (1.f + __expf(-v))) : v;
      }
    }
  }
}

// ---------------- K2: candidate-filtered exact kp argmax + offsets ----------------
// BYTE-IDENTICAL to the R8/R10-proven version (R13's gather-v2 was neutral-to-
// worse; the coalesced 6-pass staging evaluator stands).
__global__ __launch_bounds__(576) void kp_select(
    const float* __restrict__ feat, const char* __restrict__ wsb,
    float* __restrict__ out)
{
  __shared__ __align__(16) float simg[8*26*24];   // 19,968 B
  __shared__ float wk_lds[8*9*24];                //  6,912 B  [c8][k][mid]
  __shared__ float ykp [96*24];                   //  9,216 B  [group-slot][mid]
  __shared__ __align__(16) float opatch[4][432];  //  6,912 B  winner patches
  __shared__ float ymidL[4*24];                   //    384 B  winner off-mids
  __shared__ int   jobL[4*HW];                    //  9,216 B  (n<<16)|p
  __shared__ int   KtotL;
  __shared__ unsigned long long bestL[4];

  const int b = blockIdx.x, tid = threadIdx.x;
  if (tid == 0) KtotL = 0;
  if (tid < 4) bestL[tid] = 0ULL;
  __syncthreads();

  // ---- Phase 1: per-head sigmoid max + candidate collection (proven) ----
  if (tid < 256){
    const int n = tid >> 6, ln = tid & 63;
    const float* sp = out + O_KP + ((long)b*4 + n)*HW;
    float s[9];
    #pragma unroll
    for (int j = 0; j < 9; ++j) s[j] = sp[j*64 + ln];
    float mx = s[0];
    #pragma unroll
    for (int j = 1; j < 9; ++j) mx = fmaxf(mx, s[j]);
    #pragma unroll
    for (int off = 32; off >= 1; off >>= 1)
      mx = fmaxf(mx, __shfl_xor(mx, off, 64));
    const float sm = fminf(mx, 0.999999f);        // clamp: thr only gets safer
    const float thr = sm / (sm + (1.f - sm) * 1.1331485f);  // e^0.125
    #pragma unroll
    for (int j = 0; j < 9; ++j){
      if (s[j] >= thr){
        const int slot = atomicAdd(&KtotL, 1);
        jobL[slot] = (n << 16) | (j*64 + ln);
      }
    }
  }
  __syncthreads();
  const int Ktot = KtotL;

  const int s24 = tid / 24, omid = tid - s24*24;  // cand slot 0..23, mid 0..23
  const int dst = (s24 + 1)*24 + omid;            // staging dest (old mapping)
  const float* fb = feat + (size_t)b * (CIN*HW);
  const float* WKPT = (const float*)(wsb + WS_WKPT);
  const float b1k = ((const float*)(wsb + WS_B1KP))[omid];

  for (int g0 = 0; g0 < Ktot; g0 += 96){
    const int Kg = min(96, Ktot - g0);            // cands this group (uniform)

    int pyc[4], pxc[4];
    #pragma unroll
    for (int c = 0; c < 4; ++c){
      int p = 0;
      if (c*24 + s24 < Kg) p = jobL[g0 + c*24 + s24] & 0xFFFF;
      pyc[c] = p / 24; pxc[c] = p - (p/24)*24;
    }

    float acck[4] = {0.f,0.f,0.f,0.f};

    for (int pass = 0; pass < 6; ++pass){
      __syncthreads();                            // protect previous pass reads
      if (tid < 384){                             // zero pad rows 0 and 25
        int c = tid / 48, r = tid - c*48;
        int row = (r < 24) ? 0 : 25;
        int col = (r < 24) ? r : r - 24;
        simg[c*624 + row*24 + col] = 0.f;
      }
      #pragma unroll
      for (int c = 0; c < 8; ++c)
        simg[c*624 + dst] = fb[(pass*8 + c)*HW + tid];
      #pragma unroll
      for (int j = 0; j < 3; ++j)                 // 1728 = 3*576: weight slice
        wk_lds[tid + j*576] = WKPT[pass*1728 + tid + j*576];
      __syncthreads();

      for (int c8 = 0; c8 < 8; ++c8){
        float pch[4][9];
        #pragma unroll
        for (int c = 0; c < 4; ++c) if (c*24 < Kg){
          const int a = c8*624 + pyc[c]*24 + pxc[c];
          const bool wl = (pxc[c] > 0), wr = (pxc[c] < 23);
          #pragma unroll
          for (int dr = 0; dr < 3; ++dr){
            const int aa = a + dr*24;
            pch[c][dr*3+0] = wl ? simg[aa-1] : 0.f;
            pch[c][dr*3+1] = simg[aa];
            pch[c][dr*3+2] = wr ? simg[aa+1] : 0.f;
          }
        }
        const float* wkb = wk_lds + c8*216 + omid;
        #pragma unroll
        for (int k = 0; k < 9; ++k){
          const float wk = wkb[k*24];
          #pragma unroll
          for (int c = 0; c < 4; ++c) if (c*24 < Kg)
            acck[c] = fmaf(pch[c][k], wk, acck[c]);
        }
      }
    }

    // mids -> LDS
    #pragma unroll
    for (int c = 0; c < 4; ++c) if (c*24 < Kg){
      const int sl = c*24 + s24;
      ykp[sl*24 + omid] = fmaxf(acck[c] + b1k, 0.f);
    }
    __syncthreads();

    // kp layer-2 + winner update (one thread per candidate in group)
    if (tid < Kg){
      const int cand = g0 + tid;
      const int job = jobL[cand];
      const int n = job >> 16, p = job & 0xFFFF;
      const float* W2KP = (const float*)(wsb + WS_W2KP);
      float v = ((const float*)(wsb + WS_B2KP))[n];
      #pragma unroll
      for (int o = 0; o < 24; ++o)
        v = fmaf(ykp[tid*24 + o], W2KP[n*24 + o], v);
      union { float f; uint32_t u; } cv; cv.f = v;
      const uint32_t key = cv.u ^ (uint32_t)(((int32_t)cv.u >> 31) | (int32_t)0x80000000);
      const unsigned long long pk =
          ((unsigned long long)key << 32) | (unsigned)(1023 - p);
      atomicMax(&bestL[n], pk);
    }
    __syncthreads();
  }

  // ---- Phase 3: gather the 4 winners' patches global->LDS (parallel) ----
  #pragma unroll
  for (int j = 0; j < 3; ++j){
    const int e = tid*3 + j;
    const int w = e / 432, idx = e - w*432;
    const int ci = idx / 9, k = idx - ci*9;
    const int p = 1023 - (int)(bestL[w] & 0xFFFFFFFFu);
    const int py = p / 24, px = p % 24;
    const int yy = py + k/3 - 1, xx = px + (k - (k/3)*3) - 1;
    float v = 0.f;
    if (yy >= 0 && yy < 24 && xx >= 0 && xx < 24)
      v = fb[ci*HW + yy*24 + xx];
    opatch[w][idx] = v;
  }
  __syncthreads();

  // ---- Phase 4: exact off-head mids at winners (96 threads: n x mid) ----
  if (tid < 96){
    const int n = tid / 24, mid = tid - n*24;
    const float* wrow = (const float*)(wsb + WS_WOFFT) + mid*432;
    const float* prow = opatch[n];
    float s = 0.f;
    #pragma unroll 4
    for (int t = 0; t < 108; ++t){                // 108 float4 = 432 terms
      const float4 pv = *(const float4*)(prow + t*4);
      const float4 wv = *(const float4*)(wrow + t*4);
      s = fmaf(pv.x, wv.x, s);
      s = fmaf(pv.y, wv.y, s);
      s = fmaf(pv.z, wv.z, s);
      s = fmaf(pv.w, wv.w, s);
    }
    ymidL[n*24 + mid] = fmaxf(s + ((const float*)(wsb + WS_B1OFF))[mid], 0.f);
  }
  __syncthreads();

  // ---- Phase 5: off layer-2 at winners, norm/pix ----
  if (tid < 4){
    const int n = tid;
    const int p = 1023 - (int)(bestL[n] & 0xFFFFFFFFu);
    const int py = p / 24, px = p % 24;
    const float* W2OFF = (const float*)(wsb + WS_W2OFF);
    const float* B2OFF = (const float*)(wsb + WS_B2OFF);
    float ox = B2OFF[2*n], oy = B2OFF[2*n + 1];
    #pragma unroll
    for (int o = 0; o < 24; ++o){
      const float ym = ymidL[n*24 + o];
      ox = fmaf(ym, W2OFF[(2*n)*24 + o], ox);
      oy = fmaf(ym, W2OFF[(2*n + 1)*24 + o], oy);
    }
    const float fx = ((float)px + ox) * 4.f - 112.f;  // SCALE=4, X0=-112
    const float fy = ((float)py + oy) * 4.f;          // Y0=0
    out[O_NORM + b*8 + 2*n    ] = (fx + 112.f) * (1.f/336.f);
    out[O_NORM + b*8 + 2*n + 1] = fy * (1.f/224.f);
    out[O_PIX  + b*8 + 2*n    ] = fx;
    out[O_PIX  + b*8 + 2*n + 1] = fy;
  }
}

// ---------------- launch ----------------
extern "C" void kernel_launch(void* const* d_in, const int* in_sizes, int n_in,
                              void* d_out, int out_size, void* d_ws, size_t ws_size,
                              hipStream_t stream)
{
  const float* feat = (const float*)d_in[0];
  P32 P;
  for (int h = 0; h < 4; ++h){
    const int base = 1 + h*8;
    P.w1[h] = (const float*)d_in[base+0];
    P.b1[h] = (const float*)d_in[base+1];
    P.g[h]  = (const float*)d_in[base+2];
    P.be[h] = (const float*)d_in[base+3];
    P.m[h]  = (const float*)d_in[base+4];
    P.v[h]  = (const float*)d_in[base+5];
    P.w2[h] = (const float*)d_in[base+6];
    P.b2[h] = (const float*)d_in[base+7];
  }
  char* wsb = (char*)d_ws;
  float* out = (float*)d_out;

  prep_kernel<<<dim3(PREP_BLOCKS), 256, 0, stream>>>(P, wsb);
  conv_main  <<<dim3(NB),          576, 0, stream>>>(feat, wsb, out);
  kp_select  <<<dim3(NB),          576, 0, stream>>>(feat, wsb, out);
}